// Round 7
// baseline (440.548 us; speedup 1.0000x reference)
//
#include <hip/hip_runtime.h>

// Temporally-blocked Jacobi, register-resident + packed-fp32.
// v7 — grid-stride multi-tile blocks + next-tile register prefetch, 4 PLAIN
// dispatches (T=13,13,13,11). No cooperative launch (v6's failed silently).
//  * 512 blocks x 512 thr; each block runs 3-4 tiles per dispatch; tile k+1's
//    src patch (8 float4, 32 VGPR) is prefetched before tile k's step loop,
//    so HBM streams under compute instead of bursting at block start.
//  * step-loop barriers are s_waitcnt lgkmcnt(0) + raw s_barrier (memory-
//    clobber fenced): all intra-loop cross-thread deps are LDS ops, and NOT
//    draining vmcnt keeps the prefetch in flight across all T steps.
//    Tile-top barrier is a full __syncthreads() (pending vmem needed anyway).
//  * per-tile math is op-identical to v5 -> same output. Stale LDS residue
//    from the previous tile lands only in wrong-front cells (same tolerance
//    class as v5's uninitialized buf[1] halo slots).

#define NX 1024
#define BATCH 16
#define GBX 11
#define GBY 10
#define NTILES (GBX * GBY * BATCH)   // 1760
#define OUTC 96
#define T16 16           // first kept tile-local col
#define PITCH 128
#define SLOTS 34
#define NBLOCKS 512

typedef float v2f __attribute__((ext_vector_type(2)));

__device__ __forceinline__ int reflect_idx(int i) {
    i = (i < 0) ? -i : i;
    return (i > NX - 1) ? 2 * (NX - 1) - i : i;
}

__device__ __forceinline__ float dpp_wshr1(float x) {   // lane l <- lane l-1
    int v = __float_as_int(x);
    return __int_as_float(__builtin_amdgcn_update_dpp(v, v, 0x138, 0xF, 0xF, false));
}
__device__ __forceinline__ float dpp_wshl1(float x) {   // lane l <- lane l+1
    int v = __float_as_int(x);
    return __int_as_float(__builtin_amdgcn_update_dpp(v, v, 0x130, 0xF, 0xF, false));
}

__device__ __forceinline__ v2f pk_add(v2f a, v2f b) {
    v2f d; asm("v_pk_add_f32 %0, %1, %2" : "=v"(d) : "v"(a), "v"(b)); return d;
}
__device__ __forceinline__ v2f pk_fma(v2f a, v2f b, v2f c) {
    v2f d; asm("v_pk_fma_f32 %0, %1, %2, %3" : "=v"(d) : "v"(a), "v"(b), "v"(c)); return d;
}

__device__ __forceinline__ void jrow(v2f uE, v2f uO, v2f cE, v2f cO,
                                     v2f dE, v2f dO, v2f fe, v2f fo,
                                     v2f qq, v2f& rE, v2f& rO) {
    v2f vE = pk_add(uE, dE);
    v2f vO = pk_add(uO, dO);
    v2f P; P.x = dpp_wshr1(cO.y); P.y = cO.x;   // (lf, c1)
    v2f Q; Q.x = cE.y; Q.y = dpp_wshl1(cE.x);   // (c2, rt)
    v2f hE = pk_add(P, cO);                     // (lf+c1, c1+c3)
    v2f hO = pk_add(cE, Q);                     // (c0+c2, c2+rt)
    rE = pk_fma(pk_add(vE, hE), qq, fe);
    rO = pk_fma(pk_add(vO, hO), qq, fo);
}

// LDS-only barrier: drain LDS ops + block barrier, but do NOT drain vmcnt —
// keeps the next-tile prefetch global loads in flight across step barriers.
__device__ __forceinline__ void bar_lds() {
    asm volatile("s_waitcnt lgkmcnt(0)" ::: "memory");
    __builtin_amdgcn_s_barrier();
    asm volatile("" ::: "memory");
}

template<int T, int OUTR>
__device__ __forceinline__ void load_patch(const float* __restrict__ src, int t,
                                           int R0, int C0, float4 (&s4)[8]) {
    const int bx = t % GBX, rem = t / GBX, by = rem % GBY, bz = rem / GBY;
    const int gr0 = by * OUTR - T, gc0 = bx * OUTC - T16, base = bz * NX * NX;
    if (bx >= 1 && bx <= 9 && by >= 1 && by <= 8) {
        const float* sb = src + base + (gr0 + R0) * NX + gc0 + C0;
#pragma unroll
        for (int i = 0; i < 8; ++i) s4[i] = *(const float4*)(sb + i * NX);
    } else {
        const int c0 = reflect_idx(gc0 + C0), c1 = reflect_idx(gc0 + C0 + 1);
        const int c2 = reflect_idx(gc0 + C0 + 2), c3 = reflect_idx(gc0 + C0 + 3);
#pragma unroll
        for (int i = 0; i < 8; ++i) {
            const float* sr = src + base + reflect_idx(gr0 + R0 + i) * NX;
            s4[i] = make_float4(sr[c0], sr[c1], sr[c2], sr[c3]);
        }
    }
}

template<int T, int OUTR>
__global__ __launch_bounds__(512, 4) void jacobi_ms(const float* __restrict__ src,
                                                    const float* __restrict__ layout,
                                                    float* __restrict__ dst) {
    __shared__ float buf[2][SLOTS * PITCH];

    const float COF = (float)(0.25 * (0.1 / 1023.0) * (0.1 / 1023.0));

    const int tid = threadIdx.x;
    const int g = tid & 31;                      // col group: tile cols 4g..4g+3
    const int c = tid >> 5;                      // row chunk: tile rows 1+8c..8+8c
    const int R0 = 1 + 8 * c;
    const int C0 = 4 * g;
    const v2f qq = (v2f){0.25f, 0.25f};
    const int wT = (2 * c) * PITCH + C0;         // row R0   = bottom halo of chunk c-1
    const int wB = (2 * c + 3) * PITCH + C0;     // row R0+7 = top halo of chunk c+1
    const int rT = (2 * c + 1) * PITCH + C0;     // own top halo (row 8c)
    const int rB = (2 * c + 2) * PITCH + C0;     // own bottom halo (row 8c+9)

    float4 s4[8];
    load_patch<T, OUTR>(src, blockIdx.x, R0, C0, s4);   // prefetch first tile

#pragma unroll 1
    for (int t = blockIdx.x; t < NTILES; t += NBLOCKS) {
        const int bx = t % GBX, rem = t / GBX, by = rem % GBY, bz = rem / GBY;
        const int gr0 = by * OUTR - T, gc0 = bx * OUTC - T16, base = bz * NX * NX;
        const bool interior = (bx >= 1 && bx <= 9 && by >= 1 && by <= 8);

        __syncthreads();   // prev tile's LDS reads done; prefetch lands here

        // ---- pack: E/O from prefetched src; load layout + halo rows ----
        v2f E[8], O[8], fE[8], fO[8];
#pragma unroll
        for (int i = 0; i < 8; ++i) {
            E[i] = (v2f){s4[i].x, s4[i].z};
            O[i] = (v2f){s4[i].y, s4[i].w};
        }

        if (interior) {
            const float* lb = layout + base + (gr0 + R0) * NX + gc0 + C0;
#pragma unroll
            for (int i = 0; i < 8; ++i) {
                float4 v = *(const float4*)(lb + i * NX);
                fE[i] = (v2f){COF * v.x, COF * v.z};
                fO[i] = (v2f){COF * v.y, COF * v.w};
            }
            if (tid < 128) {
                const int rsel = tid >> 6, q2 = tid & 63;
                const int slot = rsel ? 32 : 1;
                v2f v = *(const v2f*)(src + base + (gr0 + (rsel ? 129 : 0)) * NX + gc0 + 2 * q2);
                const int lo = 4 * (q2 >> 1) + (q2 & 1);
                buf[0][slot * PITCH + lo]     = v.x;
                buf[0][slot * PITCH + lo + 2] = v.y;
            }
        } else {
            const int c0 = reflect_idx(gc0 + C0), c1 = reflect_idx(gc0 + C0 + 1);
            const int c2 = reflect_idx(gc0 + C0 + 2), c3 = reflect_idx(gc0 + C0 + 3);
#pragma unroll
            for (int i = 0; i < 8; ++i) {
                const float* lr = layout + base + reflect_idx(gr0 + R0 + i) * NX;
                fE[i] = (v2f){COF * lr[c0], COF * lr[c2]};
                fO[i] = (v2f){COF * lr[c1], COF * lr[c3]};
            }
            if (tid < 256) {
                const int rsel = tid >> 7, q = tid & 127;
                const int slot = rsel ? 32 : 1;
                const int grr = reflect_idx(gr0 + (rsel ? 129 : 0));
                const int lo = (q & ~3) | ((q & 1) << 1) | ((q >> 1) & 1);
                buf[0][slot * PITCH + lo] = src[base + grr * NX + reflect_idx(gc0 + q)];
            }
        }

        // publish S0 boundary rows into buf[0]
        *(v2f*)&buf[0][wT]     = E[0];
        *(v2f*)&buf[0][wT + 2] = O[0];
        *(v2f*)&buf[0][wB]     = E[7];
        *(v2f*)&buf[0][wB + 2] = O[7];

        // ---- issue next tile's src prefetch (streams under the step loop) ----
        if (t + NBLOCKS < NTILES)
            load_patch<T, OUTR>(src, t + NBLOCKS, R0, C0, s4);

        // ---- T fused steps; LDS-only barriers (vmcnt stays in flight) ----
#pragma unroll
        for (int s = 0; s < T; ++s) {
            bar_lds();
            const float* rb = buf[s & 1];
            float* wb = buf[(s + 1) & 1];
            const float4 t4 = *(const float4*)&rb[rT];
            const float4 b4 = *(const float4*)&rb[rB];

            const v2f oE0 = E[0], oO0 = O[0], oE1 = E[1], oO1 = O[1];
            v2f upE = E[0], upO = O[0];
#pragma unroll
            for (int i = 1; i <= 3; ++i) {
                v2f sE = E[i], sO = O[i];
                jrow(upE, upO, sE, sO, E[i + 1], O[i + 1], fE[i], fO[i], qq, E[i], O[i]);
                upE = sE; upO = sO;
            }
            {
                v2f topE = (v2f){t4.x, t4.y}, topO = (v2f){t4.z, t4.w};
                jrow(topE, topO, oE0, oO0, oE1, oO1, fE[0], fO[0], qq, E[0], O[0]);
            }
            if (s + 1 < T) {
                *(v2f*)&wb[wT]     = E[0];
                *(v2f*)&wb[wT + 2] = O[0];
            }
#pragma unroll
            for (int i = 4; i <= 6; ++i) {
                v2f sE = E[i], sO = O[i];
                jrow(upE, upO, sE, sO, E[i + 1], O[i + 1], fE[i], fO[i], qq, E[i], O[i]);
                upE = sE; upO = sO;
            }
            {
                v2f botE = (v2f){b4.x, b4.y}, botO = (v2f){b4.z, b4.w};
                jrow(upE, upO, E[7], O[7], botE, botO, fE[7], fO[7], qq, E[7], O[7]);
            }
            if (s + 1 < T) {
                *(v2f*)&wb[wB]     = E[7];
                *(v2f*)&wb[wB + 2] = O[7];
            }
        }

        // ---- store kept window: rows T..129-T, tile cols 16..111 ----
        const bool ok0 = (C0 >= T16) && (C0 < T16 + OUTC) && (gc0 + C0 + 1 < NX);
        const bool ok1 = (C0 + 2 >= T16) && (C0 + 2 < T16 + OUTC) && (gc0 + C0 + 3 < NX);
#pragma unroll
        for (int i = 0; i < 8; ++i) {
            const int br = R0 + i;
            const bool rowok = (br >= T) && (br <= 129 - T) && (gr0 + br < NX);
            if (rowok && ok0)
                *(v2f*)(dst + base + (gr0 + br) * NX + gc0 + C0) = (v2f){E[i].x, O[i].x};
            if (rowok && ok1)
                *(v2f*)(dst + base + (gr0 + br) * NX + gc0 + C0 + 2) = (v2f){E[i].y, O[i].y};
        }
    }
}

extern "C" void kernel_launch(void* const* d_in, const int* in_sizes, int n_in,
                              void* d_out, int out_size, void* d_ws, size_t ws_size,
                              hipStream_t stream) {
    const float* layout = (const float*)d_in[0];
    const float* heat   = (const float*)d_in[1];
    float* out = (float*)d_out;
    float* ws  = (float*)d_ws;

    const dim3 grid(NBLOCKS), block(512);

    jacobi_ms<13, 104><<<grid, block, 0, stream>>>(heat, layout, ws);
    jacobi_ms<13, 104><<<grid, block, 0, stream>>>(ws,   layout, out);
    jacobi_ms<13, 104><<<grid, block, 0, stream>>>(out,  layout, ws);
    jacobi_ms<11, 108><<<grid, block, 0, stream>>>(ws,   layout, out);
}